// Round 6
// baseline (253.350 us; speedup 1.0000x reference)
//
#include <hip/hip_runtime.h>
#include <hip/hip_bf16.h>
#include <hip/hip_cooperative_groups.h>

namespace cg = cooperative_groups;

#define NPTS 4096
#define NROWS 8192
#define DIM 128
#define GEMM_BLOCKS 1024
#define HCELL 0.25f
#define LOW (-4.0f)
#define CAP 16
#define NCELLS 32768        // 32^3 per batch
#define OVCAP 4096

typedef __attribute__((ext_vector_type(8))) short bf16x8;
typedef __attribute__((ext_vector_type(4))) float f32x4;

__device__ __forceinline__ int cellcoord(float v) {
    int c = (int)floorf((v - LOW) / HCELL);
    return c < 0 ? 0 : (c > 31 ? 31 : c);
}

// ---------- exact f64 key machinery (verified R4-R12) ----------
__device__ __forceinline__ double mkkey(float d2, int j) {
    return __longlong_as_double(__double_as_longlong((double)d2) |
                                (unsigned long long)(unsigned)j);
}
__device__ __forceinline__ void kins(double& k0, double& k1, double& k2,
                                     double& k3, double s) {
    double c = fmax(k0, s); k0 = fmin(k0, s);
    double t = fmax(k1, c); k1 = fmin(k1, c); c = t;
    t = fmax(k2, c);        k2 = fmin(k2, c); c = t;
    k3 = fmin(k3, c);
}
__device__ __forceinline__ void kmerge(double& a0, double& a1, double& a2,
                                       double& a3, double b0, double b1,
                                       double b2, double b3) {
    double m0 = fmin(a0, b3), m1 = fmin(a1, b2);
    double m2 = fmin(a2, b1), m3 = fmin(a3, b0);
    double t0 = fmin(m0, m2), t2 = fmax(m0, m2);
    double t1 = fmin(m1, m3), t3 = fmax(m1, m3);
    a0 = fmin(t0, t1); a1 = fmax(t0, t1);
    a2 = fmin(t2, t3); a3 = fmax(t2, t3);
}
__device__ __forceinline__ void wave_bfly(double& k0, double& k1,
                                          double& k2, double& k3) {
#pragma unroll
    for (int off = 1; off < 64; off <<= 1) {
        double p0 = __shfl_xor(k0, off), p1 = __shfl_xor(k1, off);
        double p2 = __shfl_xor(k2, off), p3 = __shfl_xor(k3, off);
        kmerge(k0, k1, k2, k3, p0, p1, p2, p3);
    }
}

// ---------- shared device bodies (R0-verified, used by fused AND fallback) ----------
__device__ __forceinline__ void gemm_tile_body(const float* __restrict__ x,
        const float* __restrict__ W, __hip_bfloat16* __restrict__ xWb,
        int tile, int lane) {
    int m0 = (tile >> 3) << 4, n0 = (tile & 7) << 4;
    int r = lane & 15, kg = lane >> 4;
    const float* xr = x + (size_t)(m0 + r) * DIM + kg * 8;
    const float* wc = W + (size_t)(kg * 8) * DIM + (n0 + r);
    f32x4 acc = {0.f, 0.f, 0.f, 0.f};
    union { __hip_bfloat16 h; short s; } u;
#pragma unroll
    for (int kb = 0; kb < 4; ++kb) {
        float4 a0 = *(const float4*)(xr + kb * 32);
        float4 a1 = *(const float4*)(xr + kb * 32 + 4);
        bf16x8 af, bf;
        u.h = __float2bfloat16(a0.x); af[0] = u.s;
        u.h = __float2bfloat16(a0.y); af[1] = u.s;
        u.h = __float2bfloat16(a0.z); af[2] = u.s;
        u.h = __float2bfloat16(a0.w); af[3] = u.s;
        u.h = __float2bfloat16(a1.x); af[4] = u.s;
        u.h = __float2bfloat16(a1.y); af[5] = u.s;
        u.h = __float2bfloat16(a1.z); af[6] = u.s;
        u.h = __float2bfloat16(a1.w); af[7] = u.s;
#pragma unroll
        for (int i = 0; i < 8; ++i) {
            u.h = __float2bfloat16(wc[(size_t)(kb * 32 + i) * DIM]);
            bf[i] = u.s;
        }
        acc = __builtin_amdgcn_mfma_f32_16x16x32_bf16(af, bf, acc, 0, 0, 0);
    }
    int col = n0 + r, rbase = m0 + (kg << 2);
#pragma unroll
    for (int reg = 0; reg < 4; ++reg)
        xWb[(size_t)(rbase + reg) * DIM + col] = __float2bfloat16(acc[reg]);
}

__device__ __forceinline__ void bin_point_body(const float* __restrict__ pos,
        unsigned* __restrict__ cellCnt, float4* __restrict__ cellPts,
        unsigned* __restrict__ ovfCnt, float4* __restrict__ ovfList, int t) {
    int batch = t >> 12;
    const float* p = pos + (size_t)t * 3;
    float px = p[0], py = p[1], pz = p[2];
    int cx = cellcoord(px), cy = cellcoord(py), cz = cellcoord(pz);
    int cid = ((batch * 32 + cz) * 32 + cy) * 32 + cx;
    unsigned slot = atomicAdd(&cellCnt[cid], 1u);
    float4 rec = make_float4(px, py, pz, __uint_as_float((unsigned)(t & (NPTS - 1))));
    if (slot < CAP) cellPts[(size_t)cid * CAP + slot] = rec;
    else { unsigned o = atomicAdd(&ovfCnt[batch], 1u);
           if (o < OVCAP) ovfList[(size_t)batch * OVCAP + o] = rec; }
}

__device__ __forceinline__ void knn_row_body(const unsigned* __restrict__ cellCnt,
        const float4* __restrict__ cellPts, const unsigned* __restrict__ ovfCnt,
        const float4* __restrict__ ovfList, const float* __restrict__ pos,
        const __hip_bfloat16* __restrict__ xWb, const float* __restrict__ bias,
        float* __restrict__ out, int row, int lane) {
    int batch = row >> 12;
    int qi = row & (NPTS - 1);
    const float* pb = pos + (size_t)batch * NPTS * 3;
    float qx = pb[3 * qi], qy = pb[3 * qi + 1], qz = pb[3 * qi + 2];
    int cx = cellcoord(qx), cy = cellcoord(qy), cz = cellcoord(qz);
    const unsigned* cb = cellCnt + (size_t)batch * NCELLS;
    const float4* pb4 = cellPts + (size_t)batch * NCELLS * CAP;

    const double INF = __builtin_inf();
    double k0 = INF, k1 = INF, k2 = INF, k3 = INF;

    // ---- scan 5^3 box: lane handles cells m=lane and m=lane+64 ----
#pragma unroll
    for (int mm = 0; mm < 2; ++mm) {
        int m = lane + mm * 64;
        if (m < 125) {
            int dz = m / 25 - 2, dy = (m / 5) % 5 - 2, dx = m % 5 - 2;
            int nx = cx + dx, ny = cy + dy, nz = cz + dz;
            if ((unsigned)nx < 32u && (unsigned)ny < 32u && (unsigned)nz < 32u) {
                int lid = (nz * 32 + ny) * 32 + nx;
                unsigned c = cb[lid]; c = c < CAP ? c : CAP;
                const float4* cp = pb4 + (size_t)lid * CAP;
                for (unsigned s = 0; s < c; ++s) {
                    float4 p = cp[s];
                    float ddx = qx - p.x, ddy = qy - p.y, ddz = qz - p.z;
                    float d2 = fmaf(ddx, ddx, fmaf(ddy, ddy, ddz * ddz));
                    kins(k0, k1, k2, k3, mkkey(d2, (int)__float_as_uint(p.w)));
                }
            }
        }
    }
    wave_bfly(k0, k1, k2, k3);

    // ---- exact stop check (wave-uniform; R12-verified criterion) ----
    float dbox = 1e30f;
    if (cx - 2 > 0)  dbox = fminf(dbox, qx - (LOW + (cx - 2) * HCELL));
    if (cx + 2 < 31) dbox = fminf(dbox, (LOW + (cx + 3) * HCELL) - qx);
    if (cy - 2 > 0)  dbox = fminf(dbox, qy - (LOW + (cy - 2) * HCELL));
    if (cy + 2 < 31) dbox = fminf(dbox, (LOW + (cy + 3) * HCELL) - qy);
    if (cz - 2 > 0)  dbox = fminf(dbox, qz - (LOW + (cz - 2) * HCELL));
    if (cz + 2 < 31) dbox = fminf(dbox, (LOW + (cz + 3) * HCELL) - qz);
    bool resolved = ((float)k3 < 0.999f * dbox * dbox) && ((float)k3 < 1e29f);

    if (!resolved) {
        // ---- in-wave brute scan (R4-proven, complete & exact) ----
        k0 = INF; k1 = INF; k2 = INF; k3 = INF;
#pragma unroll 4
        for (int t = 0; t < NPTS / 64; ++t) {
            int j = t * 64 + lane;
            float px = pb[3 * j], py = pb[3 * j + 1], pz = pb[3 * j + 2];
            float ddx = qx - px, ddy = qy - py, ddz = qz - pz;
            float d2 = fmaf(ddx, ddx, fmaf(ddy, ddy, ddz * ddz));
            kins(k0, k1, k2, k3, mkkey(d2, j));
        }
        wave_bfly(k0, k1, k2, k3);
    } else {
        // ---- overflow candidates (expected 0; uniform across lanes) ----
        unsigned oc = ovfCnt[batch]; oc = oc < OVCAP ? oc : OVCAP;
        const float4* ol = ovfList + (size_t)batch * OVCAP;
        for (unsigned o = 0; o < oc; ++o) {
            float4 p = ol[o];
            float ddx = qx - p.x, ddy = qy - p.y, ddz = qz - p.z;
            float d2 = fmaf(ddx, ddx, fmaf(ddy, ddy, ddz * ddz));
            kins(k0, k1, k2, k3, mkkey(d2, (int)__float_as_uint(p.w)));
        }
    }

    // ---- fused epilogue: lane owns channels (2*lane, 2*lane+1) ----
    unsigned i0 = (unsigned)__double_as_longlong(k0) & 0xFFFu;
    unsigned i1 = (unsigned)__double_as_longlong(k1) & 0xFFFu;
    unsigned i2 = (unsigned)__double_as_longlong(k2) & 0xFFFu;
    unsigned i3 = (unsigned)__double_as_longlong(k3) & 0xFFFu;
    float d0 = (float)k0, d1 = (float)k1, d2 = (float)k2, d3 = (float)k3;
    float w0 = __expf(-(d0 + 1e-8f) * 0.5f);
    float w1 = __expf(-(d1 + 1e-8f) * 0.5f);
    float w2 = __expf(-(d2 + 1e-8f) * 0.5f);
    float w3 = __expf(-(d3 + 1e-8f) * 0.5f);
    float inv = 1.0f / (w0 + w1 + w2 + w3 + 1e-8f);
    w0 *= inv; w1 *= inv; w2 *= inv; w3 *= inv;
    int c = lane << 1;
    float2 bb = *(const float2*)(bias + c);
    const unsigned short* xu = (const unsigned short*)xWb;
    size_t bbase = ((size_t)batch * NPTS) << 7;
    ushort2 g0 = *(const ushort2*)(xu + bbase + ((size_t)i0 << 7) + c);
    ushort2 g1 = *(const ushort2*)(xu + bbase + ((size_t)i1 << 7) + c);
    ushort2 g2 = *(const ushort2*)(xu + bbase + ((size_t)i2 << 7) + c);
    ushort2 g3 = *(const ushort2*)(xu + bbase + ((size_t)i3 << 7) + c);
    float ox = bb.x + w0 * __uint_as_float((unsigned)g0.x << 16)
                    + w1 * __uint_as_float((unsigned)g1.x << 16)
                    + w2 * __uint_as_float((unsigned)g2.x << 16)
                    + w3 * __uint_as_float((unsigned)g3.x << 16);
    float oy = bb.y + w0 * __uint_as_float((unsigned)g0.y << 16)
                    + w1 * __uint_as_float((unsigned)g1.y << 16)
                    + w2 * __uint_as_float((unsigned)g2.y << 16)
                    + w3 * __uint_as_float((unsigned)g3.y << 16);
    *(float2*)(out + ((size_t)row << 7) + c) = make_float2(ox, oy);
}

// ---------- fused cooperative kernel: zero -> (GEMM+bin) -> kNN+agg ----------
__global__ __launch_bounds__(256, 4) void fused(const float* __restrict__ x,
        const float* __restrict__ pos, const float* __restrict__ W,
        const float* __restrict__ bias, __hip_bfloat16* __restrict__ xWb,
        unsigned* __restrict__ cellCnt, float4* __restrict__ cellPts,
        unsigned* __restrict__ ovfCnt, float4* __restrict__ ovfList,
        float* __restrict__ out) {
    cg::grid_group gg = cg::this_grid();
    int bid = blockIdx.x, tid = threadIdx.x;
    int wave = tid >> 6, lane = tid & 63;

    // phase 0: zero cellCnt (65536 u32) + ovfCnt (2 u32, contiguous after it)
    {
        int idx = bid * 256 + tid;
        if (idx < 2 * NCELLS + 2) cellCnt[idx] = 0;
    }
    gg.sync();

    // phase 1: GEMM tile (tile = bid*4+wave, identical to R0) + binning
    gemm_tile_body(x, W, xWb, bid * 4 + wave, lane);
    if (tid < 8) bin_point_body(pos, cellCnt, cellPts, ovfCnt, ovfList,
                                bid * 8 + tid);
    gg.sync();

    // phase 2: 2 query rows per wave (R0 body)
#pragma unroll 1
    for (int rep = 0; rep < 2; ++rep)
        knn_row_body(cellCnt, cellPts, ovfCnt, ovfList, pos, xWb, bias, out,
                     bid * 8 + wave * 2 + rep, lane);
}

// ---------- fallback kernels (exact R0 3-dispatch path) ----------
__global__ __launch_bounds__(256) void k1_gemm_bin(const float* __restrict__ x,
        const float* __restrict__ pos, const float* __restrict__ W,
        __hip_bfloat16* __restrict__ xWb, unsigned* __restrict__ cellCnt,
        float4* __restrict__ cellPts, unsigned* __restrict__ ovfCnt,
        float4* __restrict__ ovfList) {
    int b = blockIdx.x;
    if (b >= GEMM_BLOCKS) {
        bin_point_body(pos, cellCnt, cellPts, ovfCnt, ovfList,
                       (b - GEMM_BLOCKS) * 256 + threadIdx.x);
        return;
    }
    gemm_tile_body(x, W, xWb, b * 4 + (threadIdx.x >> 6), threadIdx.x & 63);
}

__global__ __launch_bounds__(256) void knn_agg(const unsigned* __restrict__ cellCnt,
        const float4* __restrict__ cellPts, const unsigned* __restrict__ ovfCnt,
        const float4* __restrict__ ovfList, const float* __restrict__ pos,
        const __hip_bfloat16* __restrict__ xWb, const float* __restrict__ bias,
        float* __restrict__ out) {
    knn_row_body(cellCnt, cellPts, ovfCnt, ovfList, pos, xWb, bias, out,
                 blockIdx.x * 4 + (threadIdx.x >> 6), threadIdx.x & 63);
}

extern "C" void kernel_launch(void* const* d_in, const int* in_sizes, int n_in,
                              void* d_out, int out_size, void* d_ws, size_t ws_size,
                              hipStream_t stream) {
    const float* x    = (const float*)d_in[0];
    const float* pos  = (const float*)d_in[1];
    const float* W    = (const float*)d_in[2];
    const float* bias = (const float*)d_in[3];
    float* out = (float*)d_out;

    char* ws = (char*)d_ws;
    __hip_bfloat16* xWb = (__hip_bfloat16*)ws;                    // 2 MB
    unsigned* cellCnt  = (unsigned*)(ws + 2097152);               // 256 KB
    unsigned* ovfCnt   = (unsigned*)(ws + 2359296);               // 8 B (contiguous after cellCnt)
    float4* cellPts    = (float4*)(ws + 2359312);                 // 16 MB
    float4* ovfList    = (float4*)(ws + 2359312 + 16777216);      // 128 KB

    void* args[10] = { (void*)&x, (void*)&pos, (void*)&W, (void*)&bias,
                       (void*)&xWb, (void*)&cellCnt, (void*)&cellPts,
                       (void*)&ovfCnt, (void*)&ovfList, (void*)&out };
    hipError_t e = hipLaunchCooperativeKernel((const void*)fused, dim3(1024),
                                              dim3(256), args, 0, stream);
    if (e != hipSuccess) {
        // verified 3-dispatch R0 path (84.3us) — never produce a broken run
        hipMemsetAsync(ws + 2097152, 0, 262160, stream);
        k1_gemm_bin<<<GEMM_BLOCKS + NROWS / 256, 256, 0, stream>>>(
            x, pos, W, xWb, cellCnt, cellPts, ovfCnt, ovfList);
        knn_agg<<<NROWS / 4, 256, 0, stream>>>(
            cellCnt, cellPts, ovfCnt, ovfList, pos, xWb, bias, out);
    }
}

// Round 7
// 88.852 us; speedup vs baseline: 2.8514x; 2.8514x over previous
//
#include <hip/hip_runtime.h>
#include <hip/hip_bf16.h>

#define NPTS 4096
#define NROWS 8192
#define DIM 128
#define GEMM_BLOCKS 1024
#define HCELL 0.25f
#define LOW (-4.0f)
#define CAP 16
#define NCELLS 32768        // 32^3 per batch
#define OVCAP 4096

typedef __attribute__((ext_vector_type(8))) short bf16x8;
typedef __attribute__((ext_vector_type(4))) float f32x4;

__device__ __forceinline__ int cellcoord(float v) {
    int c = (int)floorf((v - LOW) / HCELL);
    return c < 0 ? 0 : (c > 31 ? 31 : c);
}

// ---------- K1: xW GEMM (R7-verified) + point binning (R12-verified) ----------
__global__ __launch_bounds__(256) void k1_gemm_bin(const float* __restrict__ x,
        const float* __restrict__ pos, const float* __restrict__ W,
        __hip_bfloat16* __restrict__ xWb, unsigned* __restrict__ cellCnt,
        float4* __restrict__ cellPts, unsigned* __restrict__ ovfCnt,
        float4* __restrict__ ovfList) {
    int b = blockIdx.x;
    if (b >= GEMM_BLOCKS) {
        int t = (b - GEMM_BLOCKS) * 256 + threadIdx.x;   // 0..8191
        int batch = t >> 12;
        const float* p = pos + (size_t)t * 3;
        float px = p[0], py = p[1], pz = p[2];
        int cx = cellcoord(px), cy = cellcoord(py), cz = cellcoord(pz);
        int cid = ((batch * 32 + cz) * 32 + cy) * 32 + cx;
        unsigned slot = atomicAdd(&cellCnt[cid], 1u);
        float4 rec = make_float4(px, py, pz, __uint_as_float((unsigned)(t & (NPTS - 1))));
        if (slot < CAP) cellPts[(size_t)cid * CAP + slot] = rec;
        else { unsigned o = atomicAdd(&ovfCnt[batch], 1u);
               if (o < OVCAP) ovfList[(size_t)batch * OVCAP + o] = rec; }
        return;
    }
    int wave = threadIdx.x >> 6, lane = threadIdx.x & 63;
    int tile = b * 4 + wave;
    int m0 = (tile >> 3) << 4, n0 = (tile & 7) << 4;
    int r = lane & 15, kg = lane >> 4;
    const float* xr = x + (size_t)(m0 + r) * DIM + kg * 8;
    const float* wc = W + (size_t)(kg * 8) * DIM + (n0 + r);
    f32x4 acc = {0.f, 0.f, 0.f, 0.f};
    union { __hip_bfloat16 h; short s; } u;
#pragma unroll
    for (int kb = 0; kb < 4; ++kb) {
        float4 a0 = *(const float4*)(xr + kb * 32);
        float4 a1 = *(const float4*)(xr + kb * 32 + 4);
        bf16x8 af, bf;
        u.h = __float2bfloat16(a0.x); af[0] = u.s;
        u.h = __float2bfloat16(a0.y); af[1] = u.s;
        u.h = __float2bfloat16(a0.z); af[2] = u.s;
        u.h = __float2bfloat16(a0.w); af[3] = u.s;
        u.h = __float2bfloat16(a1.x); af[4] = u.s;
        u.h = __float2bfloat16(a1.y); af[5] = u.s;
        u.h = __float2bfloat16(a1.z); af[6] = u.s;
        u.h = __float2bfloat16(a1.w); af[7] = u.s;
#pragma unroll
        for (int i = 0; i < 8; ++i) {
            u.h = __float2bfloat16(wc[(size_t)(kb * 32 + i) * DIM]);
            bf[i] = u.s;
        }
        acc = __builtin_amdgcn_mfma_f32_16x16x32_bf16(af, bf, acc, 0, 0, 0);
    }
    int col = n0 + r, rbase = m0 + (kg << 2);
#pragma unroll
    for (int reg = 0; reg < 4; ++reg)
        xWb[(size_t)(rbase + reg) * DIM + col] = __float2bfloat16(acc[reg]);
}

// ---------- exact f64 key machinery (verified R4-R12) ----------
__device__ __forceinline__ double mkkey(float d2, int j) {
    return __longlong_as_double(__double_as_longlong((double)d2) |
                                (unsigned long long)(unsigned)j);
}
__device__ __forceinline__ void kins(double& k0, double& k1, double& k2,
                                     double& k3, double s) {
    double c = fmax(k0, s); k0 = fmin(k0, s);
    double t = fmax(k1, c); k1 = fmin(k1, c); c = t;
    t = fmax(k2, c);        k2 = fmin(k2, c); c = t;
    k3 = fmin(k3, c);
}
__device__ __forceinline__ void kmerge(double& a0, double& a1, double& a2,
                                       double& a3, double b0, double b1,
                                       double b2, double b3) {
    double m0 = fmin(a0, b3), m1 = fmin(a1, b2);
    double m2 = fmin(a2, b1), m3 = fmin(a3, b0);
    double t0 = fmin(m0, m2), t2 = fmax(m0, m2);
    double t1 = fmin(m1, m3), t3 = fmax(m1, m3);
    a0 = fmin(t0, t1); a1 = fmax(t0, t1);
    a2 = fmin(t2, t3); a3 = fmax(t2, t3);
}

// ---------- K2: wave-per-2-queries interleaved grid kNN + fused epilogue ----------
// One wave = TWO query rows (rA=2p, rB=2p+1). Lane handles cell m of row A's
// 5^3 box AND cell m of row B's box in the SAME inner loop: 2 independent
// gathers in flight + 2 independent kins chains per iteration (halves the
// per-row serial latency; R6-counter evidence: kernels are ~75% latency-
// stalled, not work-bound). One butterfly carries both quads. Stop check /
// brute / overflow / epilogue are the R0-verified bodies, per row.
__global__ __launch_bounds__(256) void knn_agg(const unsigned* __restrict__ cellCnt,
        const float4* __restrict__ cellPts, const unsigned* __restrict__ ovfCnt,
        const float4* __restrict__ ovfList, const float* __restrict__ pos,
        const __hip_bfloat16* __restrict__ xWb, const float* __restrict__ bias,
        float* __restrict__ out) {
    int lane = threadIdx.x & 63;
    int wave = threadIdx.x >> 6;
    int pairI = blockIdx.x * 4 + wave;          // 0..4095
    int rA = pairI * 2, rB = rA + 1;            // never straddle a batch
    int batA = rA >> 12, batB = rB >> 12;
    int qiA = rA & (NPTS - 1), qiB = rB & (NPTS - 1);
    const float* pbA = pos + (size_t)batA * NPTS * 3;
    const float* pbB = pos + (size_t)batB * NPTS * 3;
    float qxA = pbA[3 * qiA], qyA = pbA[3 * qiA + 1], qzA = pbA[3 * qiA + 2];
    float qxB = pbB[3 * qiB], qyB = pbB[3 * qiB + 1], qzB = pbB[3 * qiB + 2];
    int cxA = cellcoord(qxA), cyA = cellcoord(qyA), czA = cellcoord(qzA);
    int cxB = cellcoord(qxB), cyB = cellcoord(qyB), czB = cellcoord(qzB);
    const unsigned* cbA = cellCnt + (size_t)batA * NCELLS;
    const unsigned* cbB = cellCnt + (size_t)batB * NCELLS;
    const float4* p4A = cellPts + (size_t)batA * NCELLS * CAP;
    const float4* p4B = cellPts + (size_t)batB * NCELLS * CAP;

    const double INF = __builtin_inf();
    double a0 = INF, a1 = INF, a2 = INF, a3 = INF;   // row A top-4
    double b0 = INF, b1 = INF, b2 = INF, b3 = INF;   // row B top-4

    // ---- interleaved 5^3 scan: cell m of A's box + cell m of B's box ----
#pragma unroll
    for (int mm = 0; mm < 2; ++mm) {
        int m = lane + mm * 64;
        int nA = 0, nB = 0;
        const float4* cpA = p4A;                // safe default; nA=0 guards
        const float4* cpB = p4B;
        if (m < 125) {
            int dz = m / 25 - 2, dy = (m / 5) % 5 - 2, dx = m % 5 - 2;
            int nx = cxA + dx, ny = cyA + dy, nz = czA + dz;
            if ((unsigned)nx < 32u && (unsigned)ny < 32u && (unsigned)nz < 32u) {
                int lid = (nz * 32 + ny) * 32 + nx;
                int c = (int)cbA[lid]; nA = c < CAP ? c : CAP;
                cpA = p4A + (size_t)lid * CAP;
            }
            nx = cxB + dx; ny = cyB + dy; nz = czB + dz;
            if ((unsigned)nx < 32u && (unsigned)ny < 32u && (unsigned)nz < 32u) {
                int lid = (nz * 32 + ny) * 32 + nx;
                int c = (int)cbB[lid]; nB = c < CAP ? c : CAP;
                cpB = p4B + (size_t)lid * CAP;
            }
        }
        int n = nA > nB ? nA : nB;
        for (int s = 0; s < n; ++s) {
            if (s < nA) {
                float4 p = cpA[s];
                float ddx = qxA - p.x, ddy = qyA - p.y, ddz = qzA - p.z;
                float d2 = fmaf(ddx, ddx, fmaf(ddy, ddy, ddz * ddz));
                kins(a0, a1, a2, a3, mkkey(d2, (int)__float_as_uint(p.w)));
            }
            if (s < nB) {
                float4 p = cpB[s];
                float ddx = qxB - p.x, ddy = qyB - p.y, ddz = qzB - p.z;
                float d2 = fmaf(ddx, ddx, fmaf(ddy, ddy, ddz * ddz));
                kins(b0, b1, b2, b3, mkkey(d2, (int)__float_as_uint(p.w)));
            }
        }
    }
    // ---- single butterfly pass carrying both rows' quads (A/B ILP) ----
#pragma unroll
    for (int off = 1; off < 64; off <<= 1) {
        double pa0 = __shfl_xor(a0, off), pa1 = __shfl_xor(a1, off);
        double pa2 = __shfl_xor(a2, off), pa3 = __shfl_xor(a3, off);
        double pb0 = __shfl_xor(b0, off), pb1 = __shfl_xor(b1, off);
        double pb2 = __shfl_xor(b2, off), pb3 = __shfl_xor(b3, off);
        kmerge(a0, a1, a2, a3, pa0, pa1, pa2, pa3);
        kmerge(b0, b1, b2, b3, pb0, pb1, pb2, pb3);
    }

    // ---- exact stop checks (wave-uniform; R12-verified criterion), per row ----
    float dbA = 1e30f;
    if (cxA - 2 > 0)  dbA = fminf(dbA, qxA - (LOW + (cxA - 2) * HCELL));
    if (cxA + 2 < 31) dbA = fminf(dbA, (LOW + (cxA + 3) * HCELL) - qxA);
    if (cyA - 2 > 0)  dbA = fminf(dbA, qyA - (LOW + (cyA - 2) * HCELL));
    if (cyA + 2 < 31) dbA = fminf(dbA, (LOW + (cyA + 3) * HCELL) - qyA);
    if (czA - 2 > 0)  dbA = fminf(dbA, qzA - (LOW + (czA - 2) * HCELL));
    if (czA + 2 < 31) dbA = fminf(dbA, (LOW + (czA + 3) * HCELL) - qzA);
    bool resA = ((float)a3 < 0.999f * dbA * dbA) && ((float)a3 < 1e29f);

    float dbB = 1e30f;
    if (cxB - 2 > 0)  dbB = fminf(dbB, qxB - (LOW + (cxB - 2) * HCELL));
    if (cxB + 2 < 31) dbB = fminf(dbB, (LOW + (cxB + 3) * HCELL) - qxB);
    if (cyB - 2 > 0)  dbB = fminf(dbB, qyB - (LOW + (cyB - 2) * HCELL));
    if (cyB + 2 < 31) dbB = fminf(dbB, (LOW + (cyB + 3) * HCELL) - qyB);
    if (czB - 2 > 0)  dbB = fminf(dbB, qzB - (LOW + (czB - 2) * HCELL));
    if (czB + 2 < 31) dbB = fminf(dbB, (LOW + (czB + 3) * HCELL) - qzB);
    bool resB = ((float)b3 < 0.999f * dbB * dbB) && ((float)b3 < 1e29f);

    if (!resA) {
        // ---- in-wave brute scan for row A (R4-proven, complete & exact) ----
        a0 = INF; a1 = INF; a2 = INF; a3 = INF;
#pragma unroll 4
        for (int t = 0; t < NPTS / 64; ++t) {
            int j = t * 64 + lane;
            float px = pbA[3 * j], py = pbA[3 * j + 1], pz = pbA[3 * j + 2];
            float ddx = qxA - px, ddy = qyA - py, ddz = qzA - pz;
            float d2 = fmaf(ddx, ddx, fmaf(ddy, ddy, ddz * ddz));
            kins(a0, a1, a2, a3, mkkey(d2, j));
        }
#pragma unroll
        for (int off = 1; off < 64; off <<= 1) {
            double p0 = __shfl_xor(a0, off), p1 = __shfl_xor(a1, off);
            double p2 = __shfl_xor(a2, off), p3 = __shfl_xor(a3, off);
            kmerge(a0, a1, a2, a3, p0, p1, p2, p3);
        }
    } else {
        unsigned oc = ovfCnt[batA]; oc = oc < OVCAP ? oc : OVCAP;
        const float4* ol = ovfList + (size_t)batA * OVCAP;
        for (unsigned o = 0; o < oc; ++o) {
            float4 p = ol[o];
            float ddx = qxA - p.x, ddy = qyA - p.y, ddz = qzA - p.z;
            float d2 = fmaf(ddx, ddx, fmaf(ddy, ddy, ddz * ddz));
            kins(a0, a1, a2, a3, mkkey(d2, (int)__float_as_uint(p.w)));
        }
    }

    if (!resB) {
        // ---- in-wave brute scan for row B ----
        b0 = INF; b1 = INF; b2 = INF; b3 = INF;
#pragma unroll 4
        for (int t = 0; t < NPTS / 64; ++t) {
            int j = t * 64 + lane;
            float px = pbB[3 * j], py = pbB[3 * j + 1], pz = pbB[3 * j + 2];
            float ddx = qxB - px, ddy = qyB - py, ddz = qzB - pz;
            float d2 = fmaf(ddx, ddx, fmaf(ddy, ddy, ddz * ddz));
            kins(b0, b1, b2, b3, mkkey(d2, j));
        }
#pragma unroll
        for (int off = 1; off < 64; off <<= 1) {
            double p0 = __shfl_xor(b0, off), p1 = __shfl_xor(b1, off);
            double p2 = __shfl_xor(b2, off), p3 = __shfl_xor(b3, off);
            kmerge(b0, b1, b2, b3, p0, p1, p2, p3);
        }
    } else {
        unsigned oc = ovfCnt[batB]; oc = oc < OVCAP ? oc : OVCAP;
        const float4* ol = ovfList + (size_t)batB * OVCAP;
        for (unsigned o = 0; o < oc; ++o) {
            float4 p = ol[o];
            float ddx = qxB - p.x, ddy = qyB - p.y, ddz = qzB - p.z;
            float d2 = fmaf(ddx, ddx, fmaf(ddy, ddy, ddz * ddz));
            kins(b0, b1, b2, b3, mkkey(d2, (int)__float_as_uint(p.w)));
        }
    }

    // ---- fused epilogue (R0 body), row A then row B ----
    int c = lane << 1;
    float2 bb = *(const float2*)(bias + c);
    const unsigned short* xu = (const unsigned short*)xWb;
    {
        unsigned i0 = (unsigned)__double_as_longlong(a0) & 0xFFFu;
        unsigned i1 = (unsigned)__double_as_longlong(a1) & 0xFFFu;
        unsigned i2 = (unsigned)__double_as_longlong(a2) & 0xFFFu;
        unsigned i3 = (unsigned)__double_as_longlong(a3) & 0xFFFu;
        float d0 = (float)a0, d1 = (float)a1, d2 = (float)a2, d3 = (float)a3;
        float w0 = __expf(-(d0 + 1e-8f) * 0.5f);
        float w1 = __expf(-(d1 + 1e-8f) * 0.5f);
        float w2 = __expf(-(d2 + 1e-8f) * 0.5f);
        float w3 = __expf(-(d3 + 1e-8f) * 0.5f);
        float inv = 1.0f / (w0 + w1 + w2 + w3 + 1e-8f);
        w0 *= inv; w1 *= inv; w2 *= inv; w3 *= inv;
        size_t bbase = ((size_t)batA * NPTS) << 7;
        ushort2 g0 = *(const ushort2*)(xu + bbase + ((size_t)i0 << 7) + c);
        ushort2 g1 = *(const ushort2*)(xu + bbase + ((size_t)i1 << 7) + c);
        ushort2 g2 = *(const ushort2*)(xu + bbase + ((size_t)i2 << 7) + c);
        ushort2 g3 = *(const ushort2*)(xu + bbase + ((size_t)i3 << 7) + c);
        float ox = bb.x + w0 * __uint_as_float((unsigned)g0.x << 16)
                        + w1 * __uint_as_float((unsigned)g1.x << 16)
                        + w2 * __uint_as_float((unsigned)g2.x << 16)
                        + w3 * __uint_as_float((unsigned)g3.x << 16);
        float oy = bb.y + w0 * __uint_as_float((unsigned)g0.y << 16)
                        + w1 * __uint_as_float((unsigned)g1.y << 16)
                        + w2 * __uint_as_float((unsigned)g2.y << 16)
                        + w3 * __uint_as_float((unsigned)g3.y << 16);
        *(float2*)(out + ((size_t)rA << 7) + c) = make_float2(ox, oy);
    }
    {
        unsigned i0 = (unsigned)__double_as_longlong(b0) & 0xFFFu;
        unsigned i1 = (unsigned)__double_as_longlong(b1) & 0xFFFu;
        unsigned i2 = (unsigned)__double_as_longlong(b2) & 0xFFFu;
        unsigned i3 = (unsigned)__double_as_longlong(b3) & 0xFFFu;
        float d0 = (float)b0, d1 = (float)b1, d2 = (float)b2, d3 = (float)b3;
        float w0 = __expf(-(d0 + 1e-8f) * 0.5f);
        float w1 = __expf(-(d1 + 1e-8f) * 0.5f);
        float w2 = __expf(-(d2 + 1e-8f) * 0.5f);
        float w3 = __expf(-(d3 + 1e-8f) * 0.5f);
        float inv = 1.0f / (w0 + w1 + w2 + w3 + 1e-8f);
        w0 *= inv; w1 *= inv; w2 *= inv; w3 *= inv;
        size_t bbase = ((size_t)batB * NPTS) << 7;
        ushort2 g0 = *(const ushort2*)(xu + bbase + ((size_t)i0 << 7) + c);
        ushort2 g1 = *(const ushort2*)(xu + bbase + ((size_t)i1 << 7) + c);
        ushort2 g2 = *(const ushort2*)(xu + bbase + ((size_t)i2 << 7) + c);
        ushort2 g3 = *(const ushort2*)(xu + bbase + ((size_t)i3 << 7) + c);
        float ox = bb.x + w0 * __uint_as_float((unsigned)g0.x << 16)
                        + w1 * __uint_as_float((unsigned)g1.x << 16)
                        + w2 * __uint_as_float((unsigned)g2.x << 16)
                        + w3 * __uint_as_float((unsigned)g3.x << 16);
        float oy = bb.y + w0 * __uint_as_float((unsigned)g0.y << 16)
                        + w1 * __uint_as_float((unsigned)g1.y << 16)
                        + w2 * __uint_as_float((unsigned)g2.y << 16)
                        + w3 * __uint_as_float((unsigned)g3.y << 16);
        *(float2*)(out + ((size_t)rB << 7) + c) = make_float2(ox, oy);
    }
}

extern "C" void kernel_launch(void* const* d_in, const int* in_sizes, int n_in,
                              void* d_out, int out_size, void* d_ws, size_t ws_size,
                              hipStream_t stream) {
    const float* x    = (const float*)d_in[0];
    const float* pos  = (const float*)d_in[1];
    const float* W    = (const float*)d_in[2];
    const float* bias = (const float*)d_in[3];
    float* out = (float*)d_out;

    char* ws = (char*)d_ws;
    __hip_bfloat16* xWb = (__hip_bfloat16*)ws;                    // 2 MB
    unsigned* cellCnt  = (unsigned*)(ws + 2097152);               // 256 KB
    unsigned* ovfCnt   = (unsigned*)(ws + 2359296);               // 16 B
    float4* cellPts    = (float4*)(ws + 2359312);                 // 16 MB
    float4* ovfList    = (float4*)(ws + 2359312 + 16777216);      // 128 KB

    hipMemsetAsync(ws + 2097152, 0, 262160, stream);              // cellCnt + ovfCnt
    k1_gemm_bin<<<GEMM_BLOCKS + NROWS / 256, 256, 0, stream>>>(
        x, pos, W, xWb, cellCnt, cellPts, ovfCnt, ovfList);
    knn_agg<<<NROWS / 8, 256, 0, stream>>>(
        cellCnt, cellPts, ovfCnt, ovfList, pos, xWb, bias, out);
}